// Round 2
// baseline (627.460 us; speedup 1.0000x reference)
//
#include <hip/hip_runtime.h>
#include <stdint.h>

// QuantizedPatternMatcher — R17: bitplane popcount, spill-free edition.
//
// R16 post-mortem: theory (bitplane VALU formulation) was sound but codegen
// spilled — VGPR_Count=128 vs ~160 live (rp+prA+prB), FETCH_SIZE 193MB vs
// ~27MB logical => ~170MB scratch traffic, VALUBusy 19%. The AMDGPU backend
// targets 4 waves/EU (128 VGPR) regardless of __launch_bounds__ min=2.
//
// R17: fit the 128-VGPR budget instead of fighting it.
//  - single pr[48] buffer (live ~110 regs), #pragma unroll 1 on pattern loop
//    so the compiler can't recreate the 160-reg live set.
//  - TLP instead of ILP for LDS latency: 32 patterns/block -> grid 512
//    (pattern-chunk fastest-varying => xplanes rows stay hot in L2),
//    2 blocks/CU, 4 waves/SIMD. amdgpu_waves_per_eu(4,4) pins the budget.
//  - per wave-pattern: 12 broadcast ds_read_b128 (uniform addr, conflict-
//    free) + ~96 int VALU. VALU floor ~10.7us chip-wide.
// Argmax = min-key (mis<<10)|pat via atomicMin (exact ref tie-break: max
// matches then lowest pattern index). Integer-exact end to end.
#define NROW 8192
#define NPAT 1024

typedef unsigned int u32;

__device__ __forceinline__ u32 bin7(float v, float e0, float e1, float e2,
                                    float e3, float e4, float e5, float e6) {
  return (u32)((v > e0) + (v > e1) + (v > e2) + (v > e3) + (v > e4) +
               (v > e5) + (v > e6));
}

__device__ __forceinline__ void acc3(u32 b, int k, u32& p0, u32& p1, u32& p2) {
  p0 |= (b & 1u) << k;
  p1 |= ((b >> 1) & 1u) << k;
  p2 |= ((b >> 2) & 1u) << k;
}

// ---------------------------------------------------------------------------
// prep: quantize + pack bitplanes.
//   xplanes [8192][16][3] u32   (48 dwords = 192 B per row; chunk-major,
//   pplanes [1024][16][3] u32    3 planes contiguous per 32-dim chunk)
//   keys    [8192] u32 = 0xFFFFFFFF  (atomicMin targets; ws re-poisoned
//                                     every iteration so must re-init)
// ---------------------------------------------------------------------------
__global__ __launch_bounds__(256) void prep_pc(
    const float* __restrict__ x, const float* __restrict__ patterns,
    const float* __restrict__ edges, u32* __restrict__ xplanes,
    u32* __restrict__ pplanes, u32* __restrict__ keys) {
  const int bid = blockIdx.x, tid = threadIdx.x;
  if (bid >= 576) {  // 32 blocks: init keys
    const int r = (bid - 576) * 256 + tid;
    keys[r] = 0xFFFFFFFFu;
    return;
  }
  const float e0 = edges[0], e1 = edges[1], e2 = edges[2], e3 = edges[3],
              e4 = edges[4], e5 = edges[5], e6 = edges[6];
  const float4* s4;
  u32* dst;
  if (bid < 512) {  // x: 8192 rows * 16 chunks = 131072 threads
    const int i = bid * 256 + tid;  // i = row*16 + chunk
    s4 = reinterpret_cast<const float4*>(x + (size_t)i * 32);
    dst = xplanes + (size_t)i * 3;
  } else {  // patterns: 1024 * 16 = 16384 threads
    const int j = (bid - 512) * 256 + tid;
    s4 = reinterpret_cast<const float4*>(patterns + (size_t)j * 32);
    dst = pplanes + (size_t)j * 3;
  }
  u32 p0 = 0, p1 = 0, p2 = 0;
#pragma unroll
  for (int q = 0; q < 8; ++q) {
    const float4 a = s4[q];
    acc3(bin7(a.x, e0, e1, e2, e3, e4, e5, e6), q * 4 + 0, p0, p1, p2);
    acc3(bin7(a.y, e0, e1, e2, e3, e4, e5, e6), q * 4 + 1, p0, p1, p2);
    acc3(bin7(a.z, e0, e1, e2, e3, e4, e5, e6), q * 4 + 2, p0, p1, p2);
    acc3(bin7(a.w, e0, e1, e2, e3, e4, e5, e6), q * 4 + 3, p0, p1, p2);
  }
  dst[0] = p0;
  dst[1] = p1;
  dst[2] = p2;
}

// ---------------------------------------------------------------------------
// match: grid 512 = 16 row-blocks (512 rows, thread=row) x 32 pattern-chunks
// (32 patterns, 6KB LDS). 512 thr = 8 waves; 2 blocks/CU = 4 waves/SIMD.
// Row planes rp[48] in VGPRs; one pattern pr[48] at a time (live ~110 regs,
// fits the pinned 128-VGPR budget — no spill). Pattern-chunk is the
// fast-varying block index so a row-block's xplanes stay hot in L2.
// ---------------------------------------------------------------------------
__global__ __launch_bounds__(512, 4)
__attribute__((amdgpu_waves_per_eu(4, 4))) void match_pc(
    const u32* __restrict__ xplanes, const u32* __restrict__ pplanes,
    u32* __restrict__ keys) {
  __shared__ __align__(16) u32 lpat[32 * 48];  // 6144 B
  const int tid = threadIdx.x;
  const int rb = blockIdx.x >> 5;
  const int pc = blockIdx.x & 31;
  const int row = rb * 512 + tid;

  // stage 32 patterns' planes (1536 dwords = 384 uint4), coalesced
  if (tid < 384) {
    reinterpret_cast<uint4*>(lpat)[tid] =
        reinterpret_cast<const uint4*>(pplanes + (size_t)pc * (32 * 48))[tid];
  }

  u32 rp[48];
  {
    const uint4* __restrict__ rs =
        reinterpret_cast<const uint4*>(xplanes + (size_t)row * 48);
#pragma unroll
    for (int j = 0; j < 12; ++j) {
      const uint4 v = rs[j];
      rp[j * 4 + 0] = v.x;
      rp[j * 4 + 1] = v.y;
      rp[j * 4 + 2] = v.z;
      rp[j * 4 + 3] = v.w;
    }
  }
  __syncthreads();

  u32 best = 0xFFFFFFFFu;
  const u32 pb = (u32)(pc << 5);
#pragma unroll 1
  for (int p = 0; p < 32; ++p) {
    u32 pr[48];
    const uint4* __restrict__ ls =
        reinterpret_cast<const uint4*>(&lpat[p * 48]);
#pragma unroll
    for (int j = 0; j < 12; ++j) {  // 12 broadcast ds_read_b128
      const uint4 v = ls[j];
      pr[j * 4 + 0] = v.x;
      pr[j * 4 + 1] = v.y;
      pr[j * 4 + 2] = v.z;
      pr[j * 4 + 3] = v.w;
    }
    u32 mis = 0;
#pragma unroll
    for (int c = 0; c < 16; ++c) {
      const u32 d = (rp[c * 3 + 0] ^ pr[c * 3 + 0]) |
                    (rp[c * 3 + 1] ^ pr[c * 3 + 1]) |
                    (rp[c * 3 + 2] ^ pr[c * 3 + 2]);
      mis += (u32)__popc(d);
    }
    const u32 key = (mis << 10) | (pb + (u32)p);
    best = key < best ? key : best;
  }
  atomicMin(&keys[row], best);
}

__global__ __launch_bounds__(256) void fixup_pc(const u32* __restrict__ keys,
                                                float* __restrict__ out) {
  const int r = blockIdx.x * 256 + threadIdx.x;
  const u32 k = keys[r];
  out[r] = (float)(k & 1023u);
  out[NROW + r] = (float)(512u - (k >> 10)) * (1.0f / 512.0f);
}

extern "C" void kernel_launch(void* const* d_in, const int* in_sizes, int n_in,
                              void* d_out, int out_size, void* d_ws,
                              size_t ws_size, hipStream_t stream) {
  const float* x = (const float*)d_in[0];         // [8192, 512] f32
  const float* patterns = (const float*)d_in[1];  // [1024, 512] f32
  const float* edges = (const float*)d_in[2];     // [7] f32
  float* out = (float*)d_out;                     // 16384 f32

  u32* xplanes = (u32*)d_ws;                       // 1.57 MB
  u32* pplanes = xplanes + (size_t)NROW * 48;      // 196 KB
  u32* keys = pplanes + (size_t)NPAT * 48;         // 32 KB

  prep_pc<<<608, 256, 0, stream>>>(x, patterns, edges, xplanes, pplanes, keys);
  match_pc<<<512, 512, 0, stream>>>(xplanes, pplanes, keys);
  fixup_pc<<<32, 256, 0, stream>>>(keys, out);
}

// Round 3
// 97.799 us; speedup vs baseline: 6.4158x; 6.4158x over previous
//
#include <hip/hip_runtime.h>
#include <stdint.h>

// QuantizedPatternMatcher — R18: bitplane popcount; pattern operand broadcast
// via the SCALAR pipe (uniform s_load), rows resident in VGPRs, no LDS.
//
// R17 post-mortem: amdgpu_waves_per_eu(4,4) made the allocator emit a 64-VGPR
// kernel against a ~110-reg live set -> 1.64GB scratch traffic, VALUBusy 4%,
// 526us. Rule reaffirmed: never pin occupancy; shrink the live set instead.
// Also re-derived: the R16/R17 LDS-broadcast structure is ~3x DS-pipe-bound
// even spill-free (12 ds_read_b128 x ~12cyc on ONE DS pipe per CU per
// 64-pair step vs 768 VALU-cyc across 4 SIMDs). Broadcast operand must not
// transit LDS.
//
// R18 structure: lane=row holds rp[48] in VGPRs (loaded once). Pattern
// address depends only on blockIdx+loop index => wave-uniform => backend
// emits s_load into SGPRs (constant cache, shared across waves); VALU reads
// it as the 1-SGPR src0 of v_xor_b32. Main loop: 0 LDS, 0 VMEM, 96 int VALU
// per 64 pairs per wave (3 xor + 2 or + 1 bcnt-accum per 32-dim chunk).
// Chip VALU floor ~10.9us. Fallback (vector loads): same-addr wave load = 1
// request, vL1-hit; live ~105 < 128 => no spill either way.
//
// Argmax = min-key (mis<<10)|pat via atomicMin (exact ref tie-break: max
// matches then lowest pattern index). Integer-exact end to end.
#define NROW 8192
#define NPAT 1024

typedef unsigned int u32;

__device__ __forceinline__ u32 bin7(float v, float e0, float e1, float e2,
                                    float e3, float e4, float e5, float e6) {
  return (u32)((v > e0) + (v > e1) + (v > e2) + (v > e3) + (v > e4) +
               (v > e5) + (v > e6));
}

__device__ __forceinline__ void acc3(u32 b, int k, u32& p0, u32& p1, u32& p2) {
  p0 |= (b & 1u) << k;
  p1 |= ((b >> 1) & 1u) << k;
  p2 |= ((b >> 2) & 1u) << k;
}

// ---------------------------------------------------------------------------
// prep: quantize + pack bitplanes.
//   xplanes [8192][16][3] u32   (48 dwords = 192 B per row; per 32-dim chunk
//   pplanes [1024][16][3] u32    the 3 planes are contiguous)
//   keys    [8192] u32 = 0xFFFFFFFF  (atomicMin targets; ws re-poisoned
//                                     every iteration so must re-init)
// ---------------------------------------------------------------------------
__global__ __launch_bounds__(256) void prep_pc(
    const float* __restrict__ x, const float* __restrict__ patterns,
    const float* __restrict__ edges, u32* __restrict__ xplanes,
    u32* __restrict__ pplanes, u32* __restrict__ keys) {
  const int bid = blockIdx.x, tid = threadIdx.x;
  if (bid >= 576) {  // 32 blocks: init keys
    const int r = (bid - 576) * 256 + tid;
    keys[r] = 0xFFFFFFFFu;
    return;
  }
  const float e0 = edges[0], e1 = edges[1], e2 = edges[2], e3 = edges[3],
              e4 = edges[4], e5 = edges[5], e6 = edges[6];
  const float4* s4;
  u32* dst;
  if (bid < 512) {  // x: 8192 rows * 16 chunks = 131072 threads
    const int i = bid * 256 + tid;  // i = row*16 + chunk
    s4 = reinterpret_cast<const float4*>(x + (size_t)i * 32);
    dst = xplanes + (size_t)i * 3;
  } else {  // patterns: 1024 * 16 = 16384 threads
    const int j = (bid - 512) * 256 + tid;
    s4 = reinterpret_cast<const float4*>(patterns + (size_t)j * 32);
    dst = pplanes + (size_t)j * 3;
  }
  u32 p0 = 0, p1 = 0, p2 = 0;
#pragma unroll
  for (int q = 0; q < 8; ++q) {
    const float4 a = s4[q];
    acc3(bin7(a.x, e0, e1, e2, e3, e4, e5, e6), q * 4 + 0, p0, p1, p2);
    acc3(bin7(a.y, e0, e1, e2, e3, e4, e5, e6), q * 4 + 1, p0, p1, p2);
    acc3(bin7(a.z, e0, e1, e2, e3, e4, e5, e6), q * 4 + 2, p0, p1, p2);
    acc3(bin7(a.w, e0, e1, e2, e3, e4, e5, e6), q * 4 + 3, p0, p1, p2);
  }
  dst[0] = p0;
  dst[1] = p1;
  dst[2] = p2;
}

// ---------------------------------------------------------------------------
// match: grid 1024 = 32 row-blocks (256 rows, thread=row) x 32 pattern-tiles
// (32 patterns). 256 thr = 4 waves; ~4 blocks/CU = 4 waves/SIMD TLP.
// Row planes rp[48] in VGPRs. Pattern planes: wave-uniform address (blockIdx
// + p only) -> scalar loads, consumed straight from SGPRs by v_xor_b32.
// No LDS, no __syncthreads. #pragma unroll 1 caps the live set (~105 regs).
// ---------------------------------------------------------------------------
__global__ __launch_bounds__(256) void match_pc(
    const u32* __restrict__ xplanes, const u32* __restrict__ pplanes,
    u32* __restrict__ keys) {
  const int tid = threadIdx.x;
  const int rb = blockIdx.x >> 5;  // row block, 0..31
  const int pc = blockIdx.x & 31;  // pattern tile, 0..31
  const int row = rb * 256 + tid;

  u32 rp[48];
  {
    const uint4* __restrict__ rs =
        reinterpret_cast<const uint4*>(xplanes + (size_t)row * 48);
#pragma unroll
    for (int j = 0; j < 12; ++j) {
      const uint4 v = rs[j];
      rp[j * 4 + 0] = v.x;
      rp[j * 4 + 1] = v.y;
      rp[j * 4 + 2] = v.z;
      rp[j * 4 + 3] = v.w;
    }
  }

  u32 best = 0xFFFFFFFFu;
  const u32 pb = (u32)(pc << 5);
  const u32* __restrict__ pp = pplanes + (size_t)pc * (32 * 48);
#pragma unroll 1
  for (int p = 0; p < 32; ++p) {
    // Wave-uniform loads (address has no threadIdx dependence) -> s_load.
    u32 sp[48];
    {
      const uint4* __restrict__ ps =
          reinterpret_cast<const uint4*>(pp + p * 48);
#pragma unroll
      for (int j = 0; j < 12; ++j) {
        const uint4 v = ps[j];
        sp[j * 4 + 0] = v.x;
        sp[j * 4 + 1] = v.y;
        sp[j * 4 + 2] = v.z;
        sp[j * 4 + 3] = v.w;
      }
    }
    u32 mis = 0;
#pragma unroll
    for (int c = 0; c < 16; ++c) {
      const u32 d = (rp[c * 3 + 0] ^ sp[c * 3 + 0]) |
                    (rp[c * 3 + 1] ^ sp[c * 3 + 1]) |
                    (rp[c * 3 + 2] ^ sp[c * 3 + 2]);
      mis += (u32)__popc(d);
    }
    const u32 key = (mis << 10) | (pb + (u32)p);
    best = key < best ? key : best;
  }
  atomicMin(&keys[row], best);
}

__global__ __launch_bounds__(256) void fixup_pc(const u32* __restrict__ keys,
                                                float* __restrict__ out) {
  const int r = blockIdx.x * 256 + threadIdx.x;
  const u32 k = keys[r];
  out[r] = (float)(k & 1023u);
  out[NROW + r] = (float)(512u - (k >> 10)) * (1.0f / 512.0f);
}

extern "C" void kernel_launch(void* const* d_in, const int* in_sizes, int n_in,
                              void* d_out, int out_size, void* d_ws,
                              size_t ws_size, hipStream_t stream) {
  const float* x = (const float*)d_in[0];         // [8192, 512] f32
  const float* patterns = (const float*)d_in[1];  // [1024, 512] f32
  const float* edges = (const float*)d_in[2];     // [7] f32
  float* out = (float*)d_out;                     // 16384 f32

  u32* xplanes = (u32*)d_ws;                       // 1.57 MB
  u32* pplanes = xplanes + (size_t)NROW * 48;      // 196 KB
  u32* keys = pplanes + (size_t)NPAT * 48;         // 32 KB

  prep_pc<<<608, 256, 0, stream>>>(x, patterns, edges, xplanes, pplanes, keys);
  match_pc<<<1024, 256, 0, stream>>>(xplanes, pplanes, keys);
  fixup_pc<<<32, 256, 0, stream>>>(keys, out);
}